// Round 3
// baseline (1150.036 us; speedup 1.0000x reference)
//
#include <hip/hip_runtime.h>
#include <stdint.h>

#define N_ITEMS   200000
#define N_USERS   16384
#define N_HIST    819200

typedef short bfrag8 __attribute__((ext_vector_type(8)));
typedef float ffrag4 __attribute__((ext_vector_type(4)));

__device__ __forceinline__ unsigned short f2bf(float f) {
    union { float f; unsigned int u; } v; v.f = f;
    unsigned int u = v.u;
    u += 0x7fffu + ((u >> 16) & 1u);   // round-to-nearest-even
    return (unsigned short)(u >> 16);
}

__device__ __forceinline__ ffrag4 mfma16(bfrag8 a, bfrag8 b, ffrag4 c) {
    return __builtin_amdgcn_mfma_f32_16x16x32_bf16(a, b, c, 0, 0, 0);
}

__device__ __forceinline__ bfrag8 pack8(float4 x0, float4 x1) {
    bfrag8 o;
    o[0] = (short)f2bf(x0.x); o[1] = (short)f2bf(x0.y);
    o[2] = (short)f2bf(x0.z); o[3] = (short)f2bf(x0.w);
    o[4] = (short)f2bf(x1.x); o[5] = (short)f2bf(x1.y);
    o[6] = (short)f2bf(x1.z); o[7] = (short)f2bf(x1.w);
    return o;
}

// ---------------------------------------------------------------------------
// K0: weight prep.
//  w1t[n*256+k]           = bf16(w1[k*256+n])                    (transpose)
//  w2s[o*256 + kt*32+g*8+j] = bf16(w2[kappa2(kt,g,j)*128 + o])   (kappa2 shuffle)
//  kappa2(kt,g,j) = (2*kt + (j>>2))*16 + 4*g + (j&3)
// ---------------------------------------------------------------------------
__global__ void cvt_all_kernel(const float* __restrict__ w1i, const float* __restrict__ w2i,
                               const float* __restrict__ w1u, const float* __restrict__ w2u,
                               unsigned short* __restrict__ o1i, unsigned short* __restrict__ o2i,
                               unsigned short* __restrict__ o1u, unsigned short* __restrict__ o2u) {
    int id = blockIdx.x * 256 + threadIdx.x;        // 0..196607
    const float* w; unsigned short* o; int local; int isW2;
    if (id < 65536)       { w = w1i; o = o1i; isW2 = 0; local = id; }
    else if (id < 98304)  { w = w2i; o = o2i; isW2 = 1; local = id - 65536; }
    else if (id < 163840) { w = w1u; o = o1u; isW2 = 0; local = id - 98304; }
    else                  { w = w2u; o = o2u; isW2 = 1; local = id - 163840; }
    if (!isW2) {
        int n = local >> 8;
        int k = local & 255;
        o[local] = f2bf(w[(size_t)k * 256 + n]);
    } else {
        int oo  = local >> 8;
        int rem = local & 255;
        int kt = rem >> 5, g = (rem >> 3) & 3, j = rem & 7;
        int k = (2 * kt + (j >> 2)) * 16 + 4 * g + (j & 3);
        o[local] = f2bf(w[(size_t)k * 128 + oo]);
    }
}

// ---------------------------------------------------------------------------
// Fused two-layer MLP tower + L2-norm. Barrier-free main loop.
// 512 threads (8 waves), 2 waves/SIMD. Each wave independently owns 16-row
// tiles (grid-stride by wave). W1^T bf16 in LDS (128K, XOR-swizzled).
// GEMM1 (swapped): h^T = mfma(W1^T-frag, x^T-frag) -> lane holds h[m=lane&15]
// for n = nt*16+4*lg+r. GEMM2 (kappa2): B-frag = lane's own relu(acc1) pack;
// A-frag = kappa2-preshuffled W2 from L2. No h LDS, no barriers, no shuffles.
// ---------------------------------------------------------------------------
#define LOAD_X(tt)  do { \
    int r_ = (tt) * 16 + lr; \
    int ra_ = rowIdxA ? rowIdxA[r_] : r_; \
    const float* pA_ = srcA + (size_t)ra_ * 128; \
    const float* pB_ = srcB + (size_t)r_ * 128; \
    _Pragma("unroll") \
    for (int kt_ = 0; kt_ < 8; ++kt_) { \
        const float* p_ = (kt_ < 4) ? (pA_ + kt_ * 32 + lg * 8) \
                                    : (pB_ + (kt_ - 4) * 32 + lg * 8); \
        a4[kt_][0] = ((const float4*)p_)[0]; \
        a4[kt_][1] = ((const float4*)p_)[1]; \
    } } while (0)

__global__ __launch_bounds__(512, 2) void tower3_kernel(
    const float* __restrict__ srcA, const float* __restrict__ srcB,
    const int* __restrict__ rowIdxA,
    const unsigned short* __restrict__ w1t, const float* __restrict__ b1,
    const unsigned short* __restrict__ w2s, const float* __restrict__ b2,
    float* __restrict__ out, unsigned short* __restrict__ mirror,
    int nTiles)
{
    __shared__ __align__(16) char smem[131072 + 1024];
    char* sW1 = smem;
    float* sB1 = (float*)(smem + 131072);

    const int tid  = threadIdx.x;
    const int lane = tid & 63;
    const int wv   = tid >> 6;
    const int lr   = lane & 15;
    const int lg   = lane >> 4;
    const int swz  = (lr & 7) << 4;          // per-lane W1 XOR swizzle

    // ---- stage W1 into LDS (swizzled), b1 into LDS ----
    {
        const uint4* g = (const uint4*)w1t;
#pragma unroll
        for (int i = 0; i < 16; ++i) {
            int c = tid + 512 * i;              // 8192 x 16B chunks
            int n = c >> 5, k16 = c & 31;
            *(uint4*)(sW1 + n * 512 + ((k16 * 16) ^ ((n & 7) << 4))) = g[c];
        }
        if (tid < 256) sB1[tid] = b1[tid];
    }
    // ---- loop-invariant b2 fragment (lane's o = ot*16 + 4*lg + r) ----
    ffrag4 b2v[8];
#pragma unroll
    for (int ot = 0; ot < 8; ++ot)
        b2v[ot] = *(const ffrag4*)(b2 + ot * 16 + 4 * lg);

    __syncthreads();                           // only barrier in the kernel

    const int stride = (int)gridDim.x * 8;
    int t = (int)blockIdx.x * 8 + wv;
    float4 a4[8][2];
    if (t < nTiles) LOAD_X(t);

    for (; t < nTiles; t += stride) {
        // ---- convert current x tile to fragments; prefetch next ----
        bfrag8 af[8];
#pragma unroll
        for (int kt = 0; kt < 8; ++kt) af[kt] = pack8(a4[kt][0], a4[kt][1]);
        int tn = t + stride;
        if (tn < nTiles) LOAD_X(tn);

        // ---- GEMM1 (swapped): acc1[nt] = h^T tile, bias-initialized ----
        ffrag4 acc1[16];
#pragma unroll
        for (int nt = 0; nt < 16; ++nt)
            acc1[nt] = *(const ffrag4*)(sB1 + nt * 16 + lg * 4);
#pragma unroll
        for (int kt = 0; kt < 8; ++kt) {
#pragma unroll
            for (int nt = 0; nt < 16; ++nt) {
                bfrag8 w1f = *(const bfrag8*)(sW1 + (nt * 16 + lr) * 512
                                              + ((kt * 64 + lg * 16) ^ swz));
                acc1[nt] = mfma16(w1f, af[kt], acc1[nt]);
            }
        }

        // ---- GEMM2 (kappa2): B-frag is lane-local relu(acc1) pack ----
        ffrag4 acc2[8];
#pragma unroll
        for (int ot = 0; ot < 8; ++ot) acc2[ot] = (ffrag4){0.f, 0.f, 0.f, 0.f};
#pragma unroll
        for (int kt = 0; kt < 8; ++kt) {
            ffrag4 lo = acc1[2 * kt], hi = acc1[2 * kt + 1];
            bfrag8 pa;
            pa[0] = (short)f2bf(fmaxf(lo[0], 0.f));
            pa[1] = (short)f2bf(fmaxf(lo[1], 0.f));
            pa[2] = (short)f2bf(fmaxf(lo[2], 0.f));
            pa[3] = (short)f2bf(fmaxf(lo[3], 0.f));
            pa[4] = (short)f2bf(fmaxf(hi[0], 0.f));
            pa[5] = (short)f2bf(fmaxf(hi[1], 0.f));
            pa[6] = (short)f2bf(fmaxf(hi[2], 0.f));
            pa[7] = (short)f2bf(fmaxf(hi[3], 0.f));
#pragma unroll
            for (int ot = 0; ot < 8; ++ot) {
                bfrag8 w2f = *(const bfrag8*)((const char*)w2s
                                              + (size_t)(ot * 16 + lr) * 512 + kt * 64 + lg * 16);
                acc2[ot] = mfma16(w2f, pa, acc2[ot]);
            }
        }

        // ---- bias + L2 norm (lane-local + 2 shuffles) + store ----
        float psum = 0.f;
#pragma unroll
        for (int ot = 0; ot < 8; ++ot) {
#pragma unroll
            for (int r = 0; r < 4; ++r) {
                float v = acc2[ot][r] + b2v[ot][r];
                acc2[ot][r] = v;
                psum += v * v;
            }
        }
        psum += __shfl_xor(psum, 16);
        psum += __shfl_xor(psum, 32);
        float sc = 1.f / fmaxf(sqrtf(psum), 1e-12f);

        int m = t * 16 + lr;
        float* orow = out + (size_t)m * 128;
#pragma unroll
        for (int ot = 0; ot < 8; ++ot) {
            float4 v4;
            v4.x = acc2[ot][0] * sc; v4.y = acc2[ot][1] * sc;
            v4.z = acc2[ot][2] * sc; v4.w = acc2[ot][3] * sc;
            *(float4*)(orow + ot * 16 + 4 * lg) = v4;
            if (mirror) {
                uint2 mm;
                mm.x = (unsigned)f2bf(v4.x) | ((unsigned)f2bf(v4.y) << 16);
                mm.y = (unsigned)f2bf(v4.z) | ((unsigned)f2bf(v4.w) << 16);
                *(uint2*)(mirror + (size_t)m * 128 + ot * 16 + 4 * lg) = mm;
            }
        }
    }
}

// ---------------------------------------------------------------------------
// K2: per-user segment mean. 4 waves/block, 1 user/wave, 2 items/iteration.
// Lane covers 4 cols (8B bf16); halves (lane>>5) take alternating items.
// ---------------------------------------------------------------------------
__global__ __launch_bounds__(256) void pool3_kernel(
    const unsigned short* __restrict__ mirror,
    const float* __restrict__ itemF,
    const int* __restrict__ histItems,
    const int* __restrict__ histSeg,
    float* __restrict__ hist)
{
    const int u = blockIdx.x * 4 + (threadIdx.x >> 6);
    const int lane = threadIdx.x & 63;
    const int half = lane >> 5;
    const int c = lane & 31;

    int lo = 0, hi = N_HIST;
    while (lo < hi) { int m = (lo + hi) >> 1; if (histSeg[m] < u) lo = m + 1; else hi = m; }
    const int s = lo;
    hi = N_HIST;
    while (lo < hi) { int m = (lo + hi) >> 1; if (histSeg[m] < u + 1) lo = m + 1; else hi = m; }
    const int e = lo;

    float s0 = 0.f, s1 = 0.f, s2 = 0.f, s3 = 0.f;
    if (mirror) {
        for (int i = s + half; i < e; i += 2) {
            int idx = histItems[i];
            uint2 v = *(const uint2*)(mirror + (size_t)idx * 128 + c * 4);
            union { unsigned u; float f; } a, b, cc, d;
            a.u  = v.x << 16; b.u  = v.x & 0xffff0000u;
            cc.u = v.y << 16; d.u  = v.y & 0xffff0000u;
            s0 += a.f; s1 += b.f; s2 += cc.f; s3 += d.f;
        }
    } else {
        for (int i = s + half; i < e; i += 2) {
            int idx = histItems[i];
            float4 v = *(const float4*)(itemF + (size_t)idx * 128 + c * 4);
            s0 += v.x; s1 += v.y; s2 += v.z; s3 += v.w;
        }
    }
    s0 += __shfl_xor(s0, 32);
    s1 += __shfl_xor(s1, 32);
    s2 += __shfl_xor(s2, 32);
    s3 += __shfl_xor(s3, 32);
    if (half == 0) {
        float inv = (e > s) ? 1.f / (float)(e - s) : 0.f;
        float4 r; r.x = s0 * inv; r.y = s1 * inv; r.z = s2 * inv; r.w = s3 * inv;
        *(float4*)(hist + (size_t)u * 128 + c * 4) = r;
    }
}

// ---------------------------------------------------------------------------
extern "C" void kernel_launch(void* const* d_in, const int* in_sizes, int n_in,
                              void* d_out, int out_size, void* d_ws, size_t ws_size,
                              hipStream_t stream) {
    const float* text    = (const float*)d_in[0];
    const float* gcnItem = (const float*)d_in[1];
    const float* gcnUser = (const float*)d_in[2];
    const float* w1i = (const float*)d_in[3];
    const float* b1i = (const float*)d_in[4];
    const float* w2i = (const float*)d_in[5];
    const float* b2i = (const float*)d_in[6];
    const float* w1u = (const float*)d_in[7];
    const float* b1u = (const float*)d_in[8];
    const float* w2u = (const float*)d_in[9];
    const float* b2u = (const float*)d_in[10];
    const int* users     = (const int*)d_in[11];
    const int* histItems = (const int*)d_in[12];
    const int* histSeg   = (const int*)d_in[13];

    float* outUser = (float*)d_out;
    float* outItem = (float*)d_out + (size_t)N_USERS * 128;

    char* ws = (char*)d_ws;
    unsigned short* w1ti = (unsigned short*)(ws + 0);        // 131072 B
    unsigned short* w2si = (unsigned short*)(ws + 131072);   // 65536 B
    unsigned short* w1tu = (unsigned short*)(ws + 196608);   // 131072 B
    unsigned short* w2su = (unsigned short*)(ws + 327680);   // 65536 B
    float*          hist = (float*)(ws + 393216);            // 8388608 B
    const size_t mirrorOff = 8781824;
    const size_t needBytes = mirrorOff + (size_t)N_ITEMS * 128 * 2;
    unsigned short* mirror = (ws_size >= needBytes) ? (unsigned short*)(ws + mirrorOff) : nullptr;

    cvt_all_kernel<<<768, 256, 0, stream>>>(w1i, w2i, w1u, w2u, w1ti, w2si, w1tu, w2su);

    tower3_kernel<<<256, 512, 0, stream>>>(
        text, gcnItem, nullptr, w1ti, b1i, w2si, b2i, outItem, mirror, N_ITEMS / 16);

    pool3_kernel<<<N_USERS / 4, 256, 0, stream>>>(mirror, outItem, histItems, histSeg, hist);

    tower3_kernel<<<128, 512, 0, stream>>>(
        gcnUser, hist, users, w1tu, b1u, w2su, b2u, outUser, nullptr, N_USERS / 16);
}

// Round 4
// 1023.995 us; speedup vs baseline: 1.1231x; 1.1231x over previous
//
#include <hip/hip_runtime.h>
#include <stdint.h>

#define N_ITEMS   200000
#define N_USERS   16384
#define N_HIST    819200

typedef short bfrag8 __attribute__((ext_vector_type(8)));
typedef float ffrag4 __attribute__((ext_vector_type(4)));

__device__ __forceinline__ unsigned short f2bf(float f) {
    union { float f; unsigned int u; } v; v.f = f;
    unsigned int u = v.u;
    u += 0x7fffu + ((u >> 16) & 1u);   // round-to-nearest-even
    return (unsigned short)(u >> 16);
}

__device__ __forceinline__ ffrag4 mfma16(bfrag8 a, bfrag8 b, ffrag4 c) {
    return __builtin_amdgcn_mfma_f32_16x16x32_bf16(a, b, c, 0, 0, 0);
}

__device__ __forceinline__ bfrag8 pack8(float4 x0, float4 x1) {
    bfrag8 o;
    o[0] = (short)f2bf(x0.x); o[1] = (short)f2bf(x0.y);
    o[2] = (short)f2bf(x0.z); o[3] = (short)f2bf(x0.w);
    o[4] = (short)f2bf(x1.x); o[5] = (short)f2bf(x1.y);
    o[6] = (short)f2bf(x1.z); o[7] = (short)f2bf(x1.w);
    return o;
}

// ---------------------------------------------------------------------------
// K0: weight prep — plain transpose + bf16 cvt for all four matrices.
//  w1t[n*256+k] = bf16(w1[k*256+n]);  w2t[o*256+k] = bf16(w2[k*128+o])
// ---------------------------------------------------------------------------
__global__ void cvt_all_kernel(const float* __restrict__ w1i, const float* __restrict__ w2i,
                               const float* __restrict__ w1u, const float* __restrict__ w2u,
                               unsigned short* __restrict__ o1i, unsigned short* __restrict__ o2i,
                               unsigned short* __restrict__ o1u, unsigned short* __restrict__ o2u) {
    int id = blockIdx.x * 256 + threadIdx.x;        // 0..196607
    const float* w; unsigned short* o; int local; int N;
    if (id < 65536)       { w = w1i; o = o1i; N = 256; local = id; }
    else if (id < 98304)  { w = w2i; o = o2i; N = 128; local = id - 65536; }
    else if (id < 163840) { w = w1u; o = o1u; N = 256; local = id - 98304; }
    else                  { w = w2u; o = o2u; N = 128; local = id - 163840; }
    int n = local >> 8;
    int k = local & 255;
    o[local] = f2bf(w[(size_t)k * N + n]);
}

// ---------------------------------------------------------------------------
// L1: h = relu([srcA||srcB] @ W1 + b1), bf16 out.  Swapped GEMM (h^T =
// mfma(W1^T, x^T)) so each lane owns full h rows -> contiguous stores.
// W1^T in XOR-swizzled LDS (128K). Barrier-free steady state, 16 rows/wave,
// grid-stride by wave, x prefetched one tile deep.
// ---------------------------------------------------------------------------
#define LOAD_X(tt)  do { \
    int r_ = (tt) * 16 + lr; \
    int ra_ = rowIdxA ? rowIdxA[r_] : r_; \
    const float* pA_ = srcA + (size_t)ra_ * 128; \
    const float* pB_ = srcB + (size_t)r_ * 128; \
    _Pragma("unroll") \
    for (int kt_ = 0; kt_ < 8; ++kt_) { \
        const float* p_ = (kt_ < 4) ? (pA_ + kt_ * 32 + lg * 8) \
                                    : (pB_ + (kt_ - 4) * 32 + lg * 8); \
        a4[kt_][0] = ((const float4*)p_)[0]; \
        a4[kt_][1] = ((const float4*)p_)[1]; \
    } } while (0)

__global__ __launch_bounds__(512, 2) void tower_l1_kernel(
    const float* __restrict__ srcA, const float* __restrict__ srcB,
    const int* __restrict__ rowIdxA,
    const unsigned short* __restrict__ w1t, const float* __restrict__ b1,
    unsigned short* __restrict__ hOut, int nTiles)
{
    __shared__ __align__(16) char smem[131072 + 1024];
    char* sW1 = smem;
    float* sB1 = (float*)(smem + 131072);

    const int tid  = threadIdx.x;
    const int lane = tid & 63;
    const int wv   = tid >> 6;
    const int lr   = lane & 15;
    const int lg   = lane >> 4;
    const int swz  = (lr & 7) << 4;

    {   // stage W1 (swizzled) + b1
        const uint4* g = (const uint4*)w1t;
#pragma unroll
        for (int i = 0; i < 16; ++i) {
            int c = tid + 512 * i;              // 8192 chunks of 16B
            int n = c >> 5, k16 = c & 31;
            *(uint4*)(sW1 + n * 512 + ((k16 * 16) ^ ((n & 7) << 4))) = g[c];
        }
        if (tid < 256) sB1[tid] = b1[tid];
    }
    __syncthreads();                            // only barrier

    const int stride = (int)gridDim.x * 8;
    int t = (int)blockIdx.x * 8 + wv;
    float4 a4[8][2];
    if (t < nTiles) LOAD_X(t);

    for (; t < nTiles; t += stride) {
        bfrag8 af[8];
#pragma unroll
        for (int kt = 0; kt < 8; ++kt) af[kt] = pack8(a4[kt][0], a4[kt][1]);
        int tn = t + stride;
        if (tn < nTiles) LOAD_X(tn);

        ffrag4 acc1[16];
#pragma unroll
        for (int nt = 0; nt < 16; ++nt)
            acc1[nt] = *(const ffrag4*)(sB1 + nt * 16 + lg * 4);
#pragma unroll
        for (int kt = 0; kt < 8; ++kt) {
#pragma unroll
            for (int nt = 0; nt < 16; ++nt) {
                bfrag8 w1f = *(const bfrag8*)(sW1 + (nt * 16 + lr) * 512
                                              + ((kt * 64 + lg * 16) ^ swz));
                acc1[nt] = mfma16(w1f, af[kt], acc1[nt]);
            }
        }

        // lane lr owns h row t*16+lr at cols nt*16+4*lg+{0..3}
        char* hrow = (char*)hOut + (size_t)(t * 16 + lr) * 512;
#pragma unroll
        for (int nt = 0; nt < 16; ++nt) {
            uint2 mm;
            mm.x = (unsigned)f2bf(fmaxf(acc1[nt][0], 0.f))
                 | ((unsigned)f2bf(fmaxf(acc1[nt][1], 0.f)) << 16);
            mm.y = (unsigned)f2bf(fmaxf(acc1[nt][2], 0.f))
                 | ((unsigned)f2bf(fmaxf(acc1[nt][3], 0.f)) << 16);
            *(uint2*)(hrow + nt * 32 + lg * 8) = mm;
        }
    }
}

// ---------------------------------------------------------------------------
// L2: y = h @ W2 + b2, L2-normalized. IN-PLACE: hIn (bf16 [rows][256]) aliases
// out (f32 [rows][128]) — same byte size per row; each row is read fully into
// registers before being overwritten by the same wave. W2^T in swizzled LDS
// (64K -> 2 blocks/CU). Swapped GEMM2: lane owns full output rows.
// ---------------------------------------------------------------------------
__global__ __launch_bounds__(512, 4) void tower_l2_kernel(
    const unsigned short* hIn,               // aliases out — no restrict!
    const unsigned short* __restrict__ w2t, const float* __restrict__ b2,
    float* out, unsigned short* __restrict__ mirror, int nTiles)
{
    __shared__ __align__(16) char sW2[65536];

    const int tid  = threadIdx.x;
    const int lane = tid & 63;
    const int wv   = tid >> 6;
    const int lr   = lane & 15;
    const int lg   = lane >> 4;
    const int swz  = (lr & 7) << 4;

    {   // stage W2^T swizzled: 4096 chunks of 16B
        const uint4* g = (const uint4*)w2t;
#pragma unroll
        for (int i = 0; i < 8; ++i) {
            int c = tid + 512 * i;
            int n = c >> 5, k16 = c & 31;
            *(uint4*)(sW2 + n * 512 + ((k16 * 16) ^ ((n & 7) << 4))) = g[c];
        }
    }
    __syncthreads();                           // only barrier

    const int stride = (int)gridDim.x * 8;
    for (int t = (int)blockIdx.x * 8 + wv; t < nTiles; t += stride) {
        // load h row lr of this tile: 8 x 16B contiguous slices (full lines)
        const char* hrow = (const char*)hIn + (size_t)(t * 16 + lr) * 512;
        bfrag8 hf[8];
#pragma unroll
        for (int kt = 0; kt < 8; ++kt)
            hf[kt] = *(const bfrag8*)(hrow + kt * 64 + lg * 16);

        ffrag4 acc2[8];
#pragma unroll
        for (int ot = 0; ot < 8; ++ot) acc2[ot] = (ffrag4){0.f, 0.f, 0.f, 0.f};
#pragma unroll
        for (int kt = 0; kt < 8; ++kt) {
#pragma unroll
            for (int ot = 0; ot < 8; ++ot) {
                bfrag8 w2f = *(const bfrag8*)(sW2 + (ot * 16 + lr) * 512
                                              + ((kt * 64 + lg * 16) ^ swz));
                acc2[ot] = mfma16(w2f, hf[kt], acc2[ot]);
            }
        }

        // bias + lane-local norm (lane holds y[row t*16+lr][o=ot*16+4lg+r])
        float psum = 0.f;
#pragma unroll
        for (int ot = 0; ot < 8; ++ot) {
            ffrag4 bv = *(const ffrag4*)(b2 + ot * 16 + 4 * lg);
#pragma unroll
            for (int r = 0; r < 4; ++r) {
                float v = acc2[ot][r] + bv[r];
                acc2[ot][r] = v;
                psum += v * v;
            }
        }
        psum += __shfl_xor(psum, 16);
        psum += __shfl_xor(psum, 32);
        float sc = 1.f / fmaxf(sqrtf(psum), 1e-12f);

        int m = t * 16 + lr;
        float* orow = out + (size_t)m * 128;
#pragma unroll
        for (int ot = 0; ot < 8; ++ot) {
            float4 v4;
            v4.x = acc2[ot][0] * sc; v4.y = acc2[ot][1] * sc;
            v4.z = acc2[ot][2] * sc; v4.w = acc2[ot][3] * sc;
            *(float4*)(orow + ot * 16 + 4 * lg) = v4;
            if (mirror) {
                uint2 mm;
                mm.x = (unsigned)f2bf(v4.x) | ((unsigned)f2bf(v4.y) << 16);
                mm.y = (unsigned)f2bf(v4.z) | ((unsigned)f2bf(v4.w) << 16);
                *(uint2*)(mirror + (size_t)m * 128 + ot * 16 + 4 * lg) = mm;
            }
        }
    }
}

// ---------------------------------------------------------------------------
// Pool: per-user segment mean. 4 waves/block, 1 user/wave, 2 items/iter.
// ---------------------------------------------------------------------------
__global__ __launch_bounds__(256) void pool3_kernel(
    const unsigned short* __restrict__ mirror,
    const float* __restrict__ itemF,
    const int* __restrict__ histItems,
    const int* __restrict__ histSeg,
    float* __restrict__ hist)
{
    const int u = blockIdx.x * 4 + (threadIdx.x >> 6);
    const int lane = threadIdx.x & 63;
    const int half = lane >> 5;
    const int c = lane & 31;

    int lo = 0, hi = N_HIST;
    while (lo < hi) { int m = (lo + hi) >> 1; if (histSeg[m] < u) lo = m + 1; else hi = m; }
    const int s = lo;
    hi = N_HIST;
    while (lo < hi) { int m = (lo + hi) >> 1; if (histSeg[m] < u + 1) lo = m + 1; else hi = m; }
    const int e = lo;

    float s0 = 0.f, s1 = 0.f, s2 = 0.f, s3 = 0.f;
    if (mirror) {
        for (int i = s + half; i < e; i += 2) {
            int idx = histItems[i];
            uint2 v = *(const uint2*)(mirror + (size_t)idx * 128 + c * 4);
            union { unsigned u; float f; } a, b, cc, d;
            a.u  = v.x << 16; b.u  = v.x & 0xffff0000u;
            cc.u = v.y << 16; d.u  = v.y & 0xffff0000u;
            s0 += a.f; s1 += b.f; s2 += cc.f; s3 += d.f;
        }
    } else {
        for (int i = s + half; i < e; i += 2) {
            int idx = histItems[i];
            float4 v = *(const float4*)(itemF + (size_t)idx * 128 + c * 4);
            s0 += v.x; s1 += v.y; s2 += v.z; s3 += v.w;
        }
    }
    s0 += __shfl_xor(s0, 32);
    s1 += __shfl_xor(s1, 32);
    s2 += __shfl_xor(s2, 32);
    s3 += __shfl_xor(s3, 32);
    if (half == 0) {
        float inv = (e > s) ? 1.f / (float)(e - s) : 0.f;
        float4 r; r.x = s0 * inv; r.y = s1 * inv; r.z = s2 * inv; r.w = s3 * inv;
        *(float4*)(hist + (size_t)u * 128 + c * 4) = r;
    }
}

// ---------------------------------------------------------------------------
extern "C" void kernel_launch(void* const* d_in, const int* in_sizes, int n_in,
                              void* d_out, int out_size, void* d_ws, size_t ws_size,
                              hipStream_t stream) {
    const float* text    = (const float*)d_in[0];
    const float* gcnItem = (const float*)d_in[1];
    const float* gcnUser = (const float*)d_in[2];
    const float* w1i = (const float*)d_in[3];
    const float* b1i = (const float*)d_in[4];
    const float* w2i = (const float*)d_in[5];
    const float* b2i = (const float*)d_in[6];
    const float* w1u = (const float*)d_in[7];
    const float* b1u = (const float*)d_in[8];
    const float* w2u = (const float*)d_in[9];
    const float* b2u = (const float*)d_in[10];
    const int* users     = (const int*)d_in[11];
    const int* histItems = (const int*)d_in[12];
    const int* histSeg   = (const int*)d_in[13];

    float* outUser = (float*)d_out;                          // [16384][128] f32
    float* outItem = (float*)d_out + (size_t)N_USERS * 128;  // [200000][128] f32
    // h buffers live IN-PLACE in the output regions (same byte size per row)
    unsigned short* hItem = (unsigned short*)outItem;        // [200000][256] bf16
    unsigned short* hUser = (unsigned short*)outUser;        // [16384][256] bf16

    char* ws = (char*)d_ws;
    unsigned short* w1ti = (unsigned short*)(ws + 0);        // 131072 B
    unsigned short* w2ti = (unsigned short*)(ws + 131072);   // 65536 B
    unsigned short* w1tu = (unsigned short*)(ws + 196608);   // 131072 B
    unsigned short* w2tu = (unsigned short*)(ws + 327680);   // 65536 B
    float*          hist = (float*)(ws + 393216);            // 8388608 B
    const size_t mirrorOff = 8781824;
    const size_t needBytes = mirrorOff + (size_t)N_ITEMS * 128 * 2;
    unsigned short* mirror = (ws_size >= needBytes) ? (unsigned short*)(ws + mirrorOff) : nullptr;

    cvt_all_kernel<<<768, 256, 0, stream>>>(w1i, w2i, w1u, w2u, w1ti, w2ti, w1tu, w2tu);

    // items: L1 (h into outItem region) -> L2 (in-place finalize + mirror)
    tower_l1_kernel<<<256, 512, 0, stream>>>(
        text, gcnItem, nullptr, w1ti, b1i, hItem, N_ITEMS / 16);
    tower_l2_kernel<<<512, 512, 0, stream>>>(
        hItem, w2ti, b2i, outItem, mirror, N_ITEMS / 16);

    pool3_kernel<<<N_USERS / 4, 256, 0, stream>>>(mirror, outItem, histItems, histSeg, hist);

    // users: gather gcn_user rows via `users`, concat with hist
    tower_l1_kernel<<<128, 512, 0, stream>>>(
        gcnUser, hist, users, w1tu, b1u, hUser, N_USERS / 16);
    tower_l2_kernel<<<128, 512, 0, stream>>>(
        hUser, w2tu, b2u, outUser, nullptr, N_USERS / 16);
}

// Round 5
// 1018.200 us; speedup vs baseline: 1.1295x; 1.0057x over previous
//
#include <hip/hip_runtime.h>
#include <stdint.h>

#define N_ITEMS   200000
#define N_USERS   16384
#define N_HIST    819200

typedef short bfrag8 __attribute__((ext_vector_type(8)));
typedef float ffrag4 __attribute__((ext_vector_type(4)));

__device__ __forceinline__ unsigned short f2bf(float f) {
    union { float f; unsigned int u; } v; v.f = f;
    unsigned int u = v.u;
    u += 0x7fffu + ((u >> 16) & 1u);   // round-to-nearest-even
    return (unsigned short)(u >> 16);
}

__device__ __forceinline__ ffrag4 mfma16(bfrag8 a, bfrag8 b, ffrag4 c) {
    return __builtin_amdgcn_mfma_f32_16x16x32_bf16(a, b, c, 0, 0, 0);
}

__device__ __forceinline__ bfrag8 pack8(float4 x0, float4 x1) {
    bfrag8 o;
    o[0] = (short)f2bf(x0.x); o[1] = (short)f2bf(x0.y);
    o[2] = (short)f2bf(x0.z); o[3] = (short)f2bf(x0.w);
    o[4] = (short)f2bf(x1.x); o[5] = (short)f2bf(x1.y);
    o[6] = (short)f2bf(x1.z); o[7] = (short)f2bf(x1.w);
    return o;
}

// ---------------------------------------------------------------------------
// K0: weight prep with kappa shuffle for ALL matrices.
//   kappa(kt,lg,j) = 32*kt + 16*(j>>2) + 4*lg + (j&3)
//   o[n*256 + kt*32 + lg*8 + j] = bf16(w[kappa * N + n])
// This makes the full-line (64B/row) global load layout a valid fragment
// layout for both x and h, with matching weight fragments.
// ---------------------------------------------------------------------------
__global__ void cvt_all_kernel(const float* __restrict__ w1i, const float* __restrict__ w2i,
                               const float* __restrict__ w1u, const float* __restrict__ w2u,
                               unsigned short* __restrict__ o1i, unsigned short* __restrict__ o2i,
                               unsigned short* __restrict__ o1u, unsigned short* __restrict__ o2u) {
    int id = blockIdx.x * 256 + threadIdx.x;        // 0..196607
    const float* w; unsigned short* o; int local; int N;
    if (id < 65536)       { w = w1i; o = o1i; N = 256; local = id; }
    else if (id < 98304)  { w = w2i; o = o2i; N = 128; local = id - 65536; }
    else if (id < 163840) { w = w1u; o = o1u; N = 256; local = id - 98304; }
    else                  { w = w2u; o = o2u; N = 128; local = id - 163840; }
    int n  = local >> 8;
    int r  = local & 255;
    int kt = r >> 5, lg = (r >> 3) & 3, j = r & 7;
    int k  = 32 * kt + 16 * (j >> 2) + 4 * lg + (j & 3);
    o[local] = f2bf(w[(size_t)k * N + n]);
}

// ---------------------------------------------------------------------------
// L1: h = relu([srcA||srcB] @ W1 + b1), kappa-packed bf16 out.
// Swapped GEMM (h^T = mfma(W1frag, xfrag)); lane owns full h rows.
// W1 (kappa-shuffled) in XOR-swizzled LDS. Barrier-free steady state,
// 16 rows/wave, grid-stride by wave, x prefetched one tile deep.
// All global accesses are full 64-B lines per row per instruction.
// ---------------------------------------------------------------------------
#define LOAD_X(tt)  do { \
    int r_ = (tt) * 16 + lr; \
    int ra_ = rowIdxA ? rowIdxA[r_] : r_; \
    const char* pA_ = (const char*)(srcA + (size_t)ra_ * 128) + lg * 16; \
    const char* pB_ = (const char*)(srcB + (size_t)r_ * 128) + lg * 16; \
    _Pragma("unroll") \
    for (int c_ = 0; c_ < 8; ++c_) a4[c_]     = *(const float4*)(pA_ + c_ * 64); \
    _Pragma("unroll") \
    for (int c_ = 0; c_ < 8; ++c_) a4[8 + c_] = *(const float4*)(pB_ + c_ * 64); \
    } while (0)

__global__ __launch_bounds__(512, 2) void tower_l1_kernel(
    const float* __restrict__ srcA, const float* __restrict__ srcB,
    const int* __restrict__ rowIdxA,
    const unsigned short* __restrict__ w1s, const float* __restrict__ b1,
    unsigned short* __restrict__ hOut, int nTiles)
{
    __shared__ __align__(16) char smem[131072 + 1024];
    char* sW1 = smem;
    float* sB1 = (float*)(smem + 131072);

    const int tid  = threadIdx.x;
    const int lane = tid & 63;
    const int wv   = tid >> 6;
    const int lr   = lane & 15;
    const int lg   = lane >> 4;
    const int swz  = (lr & 7) << 4;

    {   // stage W1 (kappa layout, XOR-swizzled) + b1
        const uint4* g = (const uint4*)w1s;
#pragma unroll
        for (int i = 0; i < 16; ++i) {
            int c = tid + 512 * i;              // 8192 chunks of 16B
            int n = c >> 5, m16 = c & 31;
            *(uint4*)(sW1 + n * 512 + ((m16 * 16) ^ ((n & 7) << 4))) = g[c];
        }
        if (tid < 256) sB1[tid] = b1[tid];
    }
    __syncthreads();                            // only barrier

    const int stride = (int)gridDim.x * 8;
    int t = (int)blockIdx.x * 8 + wv;
    float4 a4[16];
    if (t < nTiles) LOAD_X(t);

    for (; t < nTiles; t += stride) {
        bfrag8 af[8];
#pragma unroll
        for (int kt = 0; kt < 8; ++kt) af[kt] = pack8(a4[2 * kt], a4[2 * kt + 1]);
        int tn = t + stride;
        if (tn < nTiles) LOAD_X(tn);

        ffrag4 acc1[16];
#pragma unroll
        for (int nt = 0; nt < 16; ++nt)
            acc1[nt] = *(const ffrag4*)(sB1 + nt * 16 + lg * 4);
#pragma unroll
        for (int kt = 0; kt < 8; ++kt) {
#pragma unroll
            for (int nt = 0; nt < 16; ++nt) {
                bfrag8 w1f = *(const bfrag8*)(sW1 + (nt * 16 + lr) * 512
                                              + ((kt * 64 + lg * 16) ^ swz));
                acc1[nt] = mfma16(w1f, af[kt], acc1[nt]);
            }
        }

        // h store, kappa-packed: lane writes 16B at row*512 + p*64 + lg*16
        char* hrow = (char*)hOut + (size_t)(t * 16 + lr) * 512 + lg * 16;
#pragma unroll
        for (int p = 0; p < 8; ++p) {
            ffrag4 lo = acc1[2 * p], hi = acc1[2 * p + 1];
            bfrag8 hb;
            hb[0] = (short)f2bf(fmaxf(lo[0], 0.f));
            hb[1] = (short)f2bf(fmaxf(lo[1], 0.f));
            hb[2] = (short)f2bf(fmaxf(lo[2], 0.f));
            hb[3] = (short)f2bf(fmaxf(lo[3], 0.f));
            hb[4] = (short)f2bf(fmaxf(hi[0], 0.f));
            hb[5] = (short)f2bf(fmaxf(hi[1], 0.f));
            hb[6] = (short)f2bf(fmaxf(hi[2], 0.f));
            hb[7] = (short)f2bf(fmaxf(hi[3], 0.f));
            *(bfrag8*)(hrow + p * 64) = hb;
        }
    }
}

// ---------------------------------------------------------------------------
// L2: y = h @ W2 + b2, L2-normalized. IN-PLACE: hIn (kappa-packed bf16
// [rows][256]) aliases out (f32 [rows][128]); each row is fully read to regs
// by its owning wave before being overwritten. W2 (kappa) in swizzled LDS.
// h reads and out stores are full 64-B lines per row per instruction.
// ---------------------------------------------------------------------------
__global__ __launch_bounds__(512, 4) void tower_l2_kernel(
    const unsigned short* hIn,               // aliases out — no restrict!
    const unsigned short* __restrict__ w2s, const float* __restrict__ b2,
    float* out, unsigned short* __restrict__ mirror, int nTiles)
{
    __shared__ __align__(16) char smem2[65536 + 512];
    char* sW2 = smem2;
    float* sB2 = (float*)(smem2 + 65536);

    const int tid  = threadIdx.x;
    const int lane = tid & 63;
    const int wv   = tid >> 6;
    const int lr   = lane & 15;
    const int lg   = lane >> 4;
    const int swz  = (lr & 7) << 4;

    {   // stage W2 (kappa layout, swizzled) + b2
        const uint4* g = (const uint4*)w2s;
#pragma unroll
        for (int i = 0; i < 8; ++i) {
            int c = tid + 512 * i;              // 4096 chunks of 16B
            int n = c >> 5, m16 = c & 31;
            *(uint4*)(sW2 + n * 512 + ((m16 * 16) ^ ((n & 7) << 4))) = g[c];
        }
        if (tid < 128) sB2[tid] = b2[tid];
    }
    __syncthreads();                           // only barrier

    const int stride = (int)gridDim.x * 8;
    for (int t = (int)blockIdx.x * 8 + wv; t < nTiles; t += stride) {
        // load h row (kappa-packed): 8 x 16B at row*512 + kt*64 + lg*16
        const char* hrow = (const char*)hIn + (size_t)(t * 16 + lr) * 512 + lg * 16;
        bfrag8 hf[8];
#pragma unroll
        for (int kt = 0; kt < 8; ++kt)
            hf[kt] = *(const bfrag8*)(hrow + kt * 64);

        ffrag4 acc2[8];
#pragma unroll
        for (int ot = 0; ot < 8; ++ot)
            acc2[ot] = *(const ffrag4*)(sB2 + ot * 16 + lg * 4);   // bias init
#pragma unroll
        for (int kt = 0; kt < 8; ++kt) {
#pragma unroll
            for (int ot = 0; ot < 8; ++ot) {
                bfrag8 w2f = *(const bfrag8*)(sW2 + (ot * 16 + lr) * 512
                                              + ((kt * 64 + lg * 16) ^ swz));
                acc2[ot] = mfma16(w2f, hf[kt], acc2[ot]);
            }
        }

        // lane-local norm: lane holds y[row t*16+lr][ot*16+4lg+q]
        float psum = 0.f;
#pragma unroll
        for (int ot = 0; ot < 8; ++ot)
#pragma unroll
            for (int r = 0; r < 4; ++r) psum += acc2[ot][r] * acc2[ot][r];
        psum += __shfl_xor(psum, 16);
        psum += __shfl_xor(psum, 32);
        float sc = 1.f / fmaxf(sqrtf(psum), 1e-12f);

        int m = t * 16 + lr;
        float* orow = out + (size_t)m * 128 + lg * 4;
#pragma unroll
        for (int ot = 0; ot < 8; ++ot) {
            float4 v4;
            v4.x = acc2[ot][0] * sc; v4.y = acc2[ot][1] * sc;
            v4.z = acc2[ot][2] * sc; v4.w = acc2[ot][3] * sc;
            *(float4*)(orow + ot * 16) = v4;    // 64 B/row per instruction
            if (mirror) {
                uint2 mm;
                mm.x = (unsigned)f2bf(v4.x) | ((unsigned)f2bf(v4.y) << 16);
                mm.y = (unsigned)f2bf(v4.z) | ((unsigned)f2bf(v4.w) << 16);
                *(uint2*)(mirror + (size_t)m * 128 + ot * 16 + 4 * lg) = mm;
            }
        }
    }
}

// ---------------------------------------------------------------------------
// Pool: per-user segment mean. 4 waves/block, 1 user/wave, 2 items/iter.
// Mirror is plain [row][col] bf16; reads are full contiguous rows.
// ---------------------------------------------------------------------------
__global__ __launch_bounds__(256) void pool3_kernel(
    const unsigned short* __restrict__ mirror,
    const float* __restrict__ itemF,
    const int* __restrict__ histItems,
    const int* __restrict__ histSeg,
    float* __restrict__ hist)
{
    const int u = blockIdx.x * 4 + (threadIdx.x >> 6);
    const int lane = threadIdx.x & 63;
    const int half = lane >> 5;
    const int c = lane & 31;

    int lo = 0, hi = N_HIST;
    while (lo < hi) { int m = (lo + hi) >> 1; if (histSeg[m] < u) lo = m + 1; else hi = m; }
    const int s = lo;
    hi = N_HIST;
    while (lo < hi) { int m = (lo + hi) >> 1; if (histSeg[m] < u + 1) lo = m + 1; else hi = m; }
    const int e = lo;

    float s0 = 0.f, s1 = 0.f, s2 = 0.f, s3 = 0.f;
    if (mirror) {
        for (int i = s + half; i < e; i += 2) {
            int idx = histItems[i];
            uint2 v = *(const uint2*)(mirror + (size_t)idx * 128 + c * 4);
            union { unsigned u; float f; } a, b, cc, d;
            a.u  = v.x << 16; b.u  = v.x & 0xffff0000u;
            cc.u = v.y << 16; d.u  = v.y & 0xffff0000u;
            s0 += a.f; s1 += b.f; s2 += cc.f; s3 += d.f;
        }
    } else {
        for (int i = s + half; i < e; i += 2) {
            int idx = histItems[i];
            float4 v = *(const float4*)(itemF + (size_t)idx * 128 + c * 4);
            s0 += v.x; s1 += v.y; s2 += v.z; s3 += v.w;
        }
    }
    s0 += __shfl_xor(s0, 32);
    s1 += __shfl_xor(s1, 32);
    s2 += __shfl_xor(s2, 32);
    s3 += __shfl_xor(s3, 32);
    if (half == 0) {
        float inv = (e > s) ? 1.f / (float)(e - s) : 0.f;
        float4 r; r.x = s0 * inv; r.y = s1 * inv; r.z = s2 * inv; r.w = s3 * inv;
        *(float4*)(hist + (size_t)u * 128 + c * 4) = r;
    }
}

// ---------------------------------------------------------------------------
extern "C" void kernel_launch(void* const* d_in, const int* in_sizes, int n_in,
                              void* d_out, int out_size, void* d_ws, size_t ws_size,
                              hipStream_t stream) {
    const float* text    = (const float*)d_in[0];
    const float* gcnItem = (const float*)d_in[1];
    const float* gcnUser = (const float*)d_in[2];
    const float* w1i = (const float*)d_in[3];
    const float* b1i = (const float*)d_in[4];
    const float* w2i = (const float*)d_in[5];
    const float* b2i = (const float*)d_in[6];
    const float* w1u = (const float*)d_in[7];
    const float* b1u = (const float*)d_in[8];
    const float* w2u = (const float*)d_in[9];
    const float* b2u = (const float*)d_in[10];
    const int* users     = (const int*)d_in[11];
    const int* histItems = (const int*)d_in[12];
    const int* histSeg   = (const int*)d_in[13];

    float* outUser = (float*)d_out;                          // [16384][128] f32
    float* outItem = (float*)d_out + (size_t)N_USERS * 128;  // [200000][128] f32
    // h buffers live IN-PLACE in the output regions (same byte size per row)
    unsigned short* hItem = (unsigned short*)outItem;        // kappa-packed
    unsigned short* hUser = (unsigned short*)outUser;

    char* ws = (char*)d_ws;
    unsigned short* w1si = (unsigned short*)(ws + 0);        // 131072 B
    unsigned short* w2si = (unsigned short*)(ws + 131072);   // 65536 B
    unsigned short* w1su = (unsigned short*)(ws + 196608);   // 131072 B
    unsigned short* w2su = (unsigned short*)(ws + 327680);   // 65536 B
    float*          hist = (float*)(ws + 393216);            // 8388608 B
    const size_t mirrorOff = 8781824;
    const size_t needBytes = mirrorOff + (size_t)N_ITEMS * 128 * 2;
    unsigned short* mirror = (ws_size >= needBytes) ? (unsigned short*)(ws + mirrorOff) : nullptr;

    cvt_all_kernel<<<768, 256, 0, stream>>>(w1i, w2i, w1u, w2u, w1si, w2si, w1su, w2su);

    // items: L1 (kappa-h into outItem region) -> L2 (in-place finalize + mirror)
    tower_l1_kernel<<<256, 512, 0, stream>>>(
        text, gcnItem, nullptr, w1si, b1i, hItem, N_ITEMS / 16);
    tower_l2_kernel<<<512, 512, 0, stream>>>(
        hItem, w2si, b2i, outItem, mirror, N_ITEMS / 16);

    pool3_kernel<<<N_USERS / 4, 256, 0, stream>>>(mirror, outItem, histItems, histSeg, hist);

    // users: gather gcn_user rows via `users`, concat with hist
    tower_l1_kernel<<<128, 512, 0, stream>>>(
        gcnUser, hist, users, w1su, b1u, hUser, N_USERS / 16);
    tower_l2_kernel<<<128, 512, 0, stream>>>(
        hUser, w2su, b2u, outUser, nullptr, N_USERS / 16);
}

// Round 6
// 885.408 us; speedup vs baseline: 1.2989x; 1.1500x over previous
//
#include <hip/hip_runtime.h>
#include <stdint.h>

#define N_ITEMS   200000
#define N_USERS   16384
#define N_HIST    819200

typedef short bfrag8 __attribute__((ext_vector_type(8)));
typedef float ffrag4 __attribute__((ext_vector_type(4)));

__device__ __forceinline__ unsigned short f2bf(float f) {
    union { float f; unsigned int u; } v; v.f = f;
    unsigned int u = v.u;
    u += 0x7fffu + ((u >> 16) & 1u);   // round-to-nearest-even
    return (unsigned short)(u >> 16);
}

__device__ __forceinline__ ffrag4 mfma16(bfrag8 a, bfrag8 b, ffrag4 c) {
    return __builtin_amdgcn_mfma_f32_16x16x32_bf16(a, b, c, 0, 0, 0);
}

__device__ __forceinline__ bfrag8 pack8(float4 x0, float4 x1) {
    bfrag8 o;
    o[0] = (short)f2bf(x0.x); o[1] = (short)f2bf(x0.y);
    o[2] = (short)f2bf(x0.z); o[3] = (short)f2bf(x0.w);
    o[4] = (short)f2bf(x1.x); o[5] = (short)f2bf(x1.y);
    o[6] = (short)f2bf(x1.z); o[7] = (short)f2bf(x1.w);
    return o;
}

// ---------------------------------------------------------------------------
// K0: weight prep with kappa shuffle for ALL matrices.
//   kappa(kt,lg,j) = 32*kt + 16*(j>>2) + 4*lg + (j&3)
//   o[n*256 + kt*32 + lg*8 + j] = bf16(w[kappa * N + n])
// ---------------------------------------------------------------------------
__global__ void cvt_all_kernel(const float* __restrict__ w1i, const float* __restrict__ w2i,
                               const float* __restrict__ w1u, const float* __restrict__ w2u,
                               unsigned short* __restrict__ o1i, unsigned short* __restrict__ o2i,
                               unsigned short* __restrict__ o1u, unsigned short* __restrict__ o2u) {
    int id = blockIdx.x * 256 + threadIdx.x;        // 0..196607
    const float* w; unsigned short* o; int local; int N;
    if (id < 65536)       { w = w1i; o = o1i; N = 256; local = id; }
    else if (id < 98304)  { w = w2i; o = o2i; N = 128; local = id - 65536; }
    else if (id < 163840) { w = w1u; o = o1u; N = 256; local = id - 98304; }
    else                  { w = w2u; o = o2u; N = 128; local = id - 163840; }
    int n  = local >> 8;
    int r  = local & 255;
    int kt = r >> 5, lg = (r >> 3) & 3, j = r & 7;
    int k  = 32 * kt + 16 * (j >> 2) + 4 * lg + (j & 3);
    o[local] = f2bf(w[(size_t)k * N + n]);
}

// ---------------------------------------------------------------------------
// L1: h = relu([srcA||srcB] @ W1 + b1), kappa-packed bf16 out.
// Swapped GEMM (h^T = mfma(W1frag, xfrag)); lane owns full h rows.
// W1 (kappa-shuffled) in XOR-swizzled LDS. Barrier-free steady state,
// 16 rows/wave, grid-stride by wave, x prefetched one tile deep.
// __launch_bounds__(512,1): 256-VGPR cap — the kernel needs ~200 live regs
// (a4 64 + af 32 + acc1 64 + misc); (512,2)'s 128-cap caused catastrophic
// scratch spilling (914 MB FETCH, 2% MfmaUtil in rounds 3-5).
// ---------------------------------------------------------------------------
#define LOAD_X(tt)  do { \
    int r_ = (tt) * 16 + lr; \
    int ra_ = rowIdxA ? rowIdxA[r_] : r_; \
    const char* pA_ = (const char*)(srcA + (size_t)ra_ * 128) + lg * 16; \
    const char* pB_ = (const char*)(srcB + (size_t)r_ * 128) + lg * 16; \
    _Pragma("unroll") \
    for (int c_ = 0; c_ < 8; ++c_) a4[c_]     = *(const float4*)(pA_ + c_ * 64); \
    _Pragma("unroll") \
    for (int c_ = 0; c_ < 8; ++c_) a4[8 + c_] = *(const float4*)(pB_ + c_ * 64); \
    } while (0)

__global__ __launch_bounds__(512, 1) void tower_l1_kernel(
    const float* __restrict__ srcA, const float* __restrict__ srcB,
    const int* __restrict__ rowIdxA,
    const unsigned short* __restrict__ w1s, const float* __restrict__ b1,
    unsigned short* __restrict__ hOut, int nTiles)
{
    __shared__ __align__(16) char smem[131072 + 1024];
    char* sW1 = smem;
    float* sB1 = (float*)(smem + 131072);

    const int tid  = threadIdx.x;
    const int lane = tid & 63;
    const int wv   = tid >> 6;
    const int lr   = lane & 15;
    const int lg   = lane >> 4;
    const int swz  = (lr & 7) << 4;

    {   // stage W1 (kappa layout, XOR-swizzled) + b1
        const uint4* g = (const uint4*)w1s;
#pragma unroll
        for (int i = 0; i < 16; ++i) {
            int c = tid + 512 * i;              // 8192 chunks of 16B
            int n = c >> 5, m16 = c & 31;
            *(uint4*)(sW1 + n * 512 + ((m16 * 16) ^ ((n & 7) << 4))) = g[c];
        }
        if (tid < 256) sB1[tid] = b1[tid];
    }
    __syncthreads();                            // only barrier

    const int stride = (int)gridDim.x * 8;
    int t = (int)blockIdx.x * 8 + wv;
    float4 a4[16];
    if (t < nTiles) LOAD_X(t);

    for (; t < nTiles; t += stride) {
        bfrag8 af[8];
#pragma unroll
        for (int kt = 0; kt < 8; ++kt) af[kt] = pack8(a4[2 * kt], a4[2 * kt + 1]);
        int tn = t + stride;
        if (tn < nTiles) LOAD_X(tn);

        ffrag4 acc1[16];
#pragma unroll
        for (int nt = 0; nt < 16; ++nt)
            acc1[nt] = *(const ffrag4*)(sB1 + nt * 16 + lg * 4);
#pragma unroll
        for (int kt = 0; kt < 8; ++kt) {
#pragma unroll
            for (int nt = 0; nt < 16; ++nt) {
                bfrag8 w1f = *(const bfrag8*)(sW1 + (nt * 16 + lr) * 512
                                              + ((kt * 64 + lg * 16) ^ swz));
                acc1[nt] = mfma16(w1f, af[kt], acc1[nt]);
            }
        }

        // h store, kappa-packed: lane writes 16B at row*512 + p*64 + lg*16
        char* hrow = (char*)hOut + (size_t)(t * 16 + lr) * 512 + lg * 16;
#pragma unroll
        for (int p = 0; p < 8; ++p) {
            ffrag4 lo = acc1[2 * p], hi = acc1[2 * p + 1];
            bfrag8 hb;
            hb[0] = (short)f2bf(fmaxf(lo[0], 0.f));
            hb[1] = (short)f2bf(fmaxf(lo[1], 0.f));
            hb[2] = (short)f2bf(fmaxf(lo[2], 0.f));
            hb[3] = (short)f2bf(fmaxf(lo[3], 0.f));
            hb[4] = (short)f2bf(fmaxf(hi[0], 0.f));
            hb[5] = (short)f2bf(fmaxf(hi[1], 0.f));
            hb[6] = (short)f2bf(fmaxf(hi[2], 0.f));
            hb[7] = (short)f2bf(fmaxf(hi[3], 0.f));
            *(bfrag8*)(hrow + p * 64) = hb;
        }
    }
}

// ---------------------------------------------------------------------------
// L2: y = h @ W2 + b2, L2-normalized. IN-PLACE: hIn (kappa-packed bf16
// [rows][256]) aliases out (f32 [rows][128]); each row fully read to regs by
// its owning wave before overwrite. W2 (kappa) in swizzled LDS.
// __launch_bounds__(512,2): 128-VGPR cap, ~100 live (hf 32 + acc2 32 + misc);
// the previous (512,4) 64-reg cap caused spilling.
// ---------------------------------------------------------------------------
__global__ __launch_bounds__(512, 2) void tower_l2_kernel(
    const unsigned short* hIn,               // aliases out — no restrict!
    const unsigned short* __restrict__ w2s, const float* __restrict__ b2,
    float* out, unsigned short* __restrict__ mirror, int nTiles)
{
    __shared__ __align__(16) char smem2[65536 + 512];
    char* sW2 = smem2;
    float* sB2 = (float*)(smem2 + 65536);

    const int tid  = threadIdx.x;
    const int lane = tid & 63;
    const int wv   = tid >> 6;
    const int lr   = lane & 15;
    const int lg   = lane >> 4;
    const int swz  = (lr & 7) << 4;

    {   // stage W2 (kappa layout, swizzled) + b2
        const uint4* g = (const uint4*)w2s;
#pragma unroll
        for (int i = 0; i < 8; ++i) {
            int c = tid + 512 * i;              // 4096 chunks of 16B
            int n = c >> 5, m16 = c & 31;
            *(uint4*)(sW2 + n * 512 + ((m16 * 16) ^ ((n & 7) << 4))) = g[c];
        }
        if (tid < 128) sB2[tid] = b2[tid];
    }
    __syncthreads();                           // only barrier

    const int stride = (int)gridDim.x * 8;
    for (int t = (int)blockIdx.x * 8 + wv; t < nTiles; t += stride) {
        // load h row (kappa-packed): 8 x 16B at row*512 + kt*64 + lg*16
        const char* hrow = (const char*)hIn + (size_t)(t * 16 + lr) * 512 + lg * 16;
        bfrag8 hf[8];
#pragma unroll
        for (int kt = 0; kt < 8; ++kt)
            hf[kt] = *(const bfrag8*)(hrow + kt * 64);

        ffrag4 acc2[8];
#pragma unroll
        for (int ot = 0; ot < 8; ++ot)
            acc2[ot] = *(const ffrag4*)(sB2 + ot * 16 + lg * 4);   // bias init
#pragma unroll
        for (int kt = 0; kt < 8; ++kt) {
#pragma unroll
            for (int ot = 0; ot < 8; ++ot) {
                bfrag8 w2f = *(const bfrag8*)(sW2 + (ot * 16 + lr) * 512
                                              + ((kt * 64 + lg * 16) ^ swz));
                acc2[ot] = mfma16(w2f, hf[kt], acc2[ot]);
            }
        }

        // lane-local norm: lane holds y[row t*16+lr][ot*16+4lg+q]
        float psum = 0.f;
#pragma unroll
        for (int ot = 0; ot < 8; ++ot)
#pragma unroll
            for (int r = 0; r < 4; ++r) psum += acc2[ot][r] * acc2[ot][r];
        psum += __shfl_xor(psum, 16);
        psum += __shfl_xor(psum, 32);
        float sc = 1.f / fmaxf(sqrtf(psum), 1e-12f);

        int m = t * 16 + lr;
        float* orow = out + (size_t)m * 128 + lg * 4;
#pragma unroll
        for (int ot = 0; ot < 8; ++ot) {
            float4 v4;
            v4.x = acc2[ot][0] * sc; v4.y = acc2[ot][1] * sc;
            v4.z = acc2[ot][2] * sc; v4.w = acc2[ot][3] * sc;
            *(float4*)(orow + ot * 16) = v4;    // 64 B/row per instruction
            if (mirror) {
                uint2 mm;
                mm.x = (unsigned)f2bf(v4.x) | ((unsigned)f2bf(v4.y) << 16);
                mm.y = (unsigned)f2bf(v4.z) | ((unsigned)f2bf(v4.w) << 16);
                *(uint2*)(mirror + (size_t)m * 128 + ot * 16 + 4 * lg) = mm;
            }
        }
    }
}

// ---------------------------------------------------------------------------
// Pool: per-user segment mean. 4 waves/block, 1 user/wave, 2 items/iter.
// ---------------------------------------------------------------------------
__global__ __launch_bounds__(256) void pool3_kernel(
    const unsigned short* __restrict__ mirror,
    const float* __restrict__ itemF,
    const int* __restrict__ histItems,
    const int* __restrict__ histSeg,
    float* __restrict__ hist)
{
    const int u = blockIdx.x * 4 + (threadIdx.x >> 6);
    const int lane = threadIdx.x & 63;
    const int half = lane >> 5;
    const int c = lane & 31;

    int lo = 0, hi = N_HIST;
    while (lo < hi) { int m = (lo + hi) >> 1; if (histSeg[m] < u) lo = m + 1; else hi = m; }
    const int s = lo;
    hi = N_HIST;
    while (lo < hi) { int m = (lo + hi) >> 1; if (histSeg[m] < u + 1) lo = m + 1; else hi = m; }
    const int e = lo;

    float s0 = 0.f, s1 = 0.f, s2 = 0.f, s3 = 0.f;
    if (mirror) {
        for (int i = s + half; i < e; i += 2) {
            int idx = histItems[i];
            uint2 v = *(const uint2*)(mirror + (size_t)idx * 128 + c * 4);
            union { unsigned u; float f; } a, b, cc, d;
            a.u  = v.x << 16; b.u  = v.x & 0xffff0000u;
            cc.u = v.y << 16; d.u  = v.y & 0xffff0000u;
            s0 += a.f; s1 += b.f; s2 += cc.f; s3 += d.f;
        }
    } else {
        for (int i = s + half; i < e; i += 2) {
            int idx = histItems[i];
            float4 v = *(const float4*)(itemF + (size_t)idx * 128 + c * 4);
            s0 += v.x; s1 += v.y; s2 += v.z; s3 += v.w;
        }
    }
    s0 += __shfl_xor(s0, 32);
    s1 += __shfl_xor(s1, 32);
    s2 += __shfl_xor(s2, 32);
    s3 += __shfl_xor(s3, 32);
    if (half == 0) {
        float inv = (e > s) ? 1.f / (float)(e - s) : 0.f;
        float4 r; r.x = s0 * inv; r.y = s1 * inv; r.z = s2 * inv; r.w = s3 * inv;
        *(float4*)(hist + (size_t)u * 128 + c * 4) = r;
    }
}

// ---------------------------------------------------------------------------
extern "C" void kernel_launch(void* const* d_in, const int* in_sizes, int n_in,
                              void* d_out, int out_size, void* d_ws, size_t ws_size,
                              hipStream_t stream) {
    const float* text    = (const float*)d_in[0];
    const float* gcnItem = (const float*)d_in[1];
    const float* gcnUser = (const float*)d_in[2];
    const float* w1i = (const float*)d_in[3];
    const float* b1i = (const float*)d_in[4];
    const float* w2i = (const float*)d_in[5];
    const float* b2i = (const float*)d_in[6];
    const float* w1u = (const float*)d_in[7];
    const float* b1u = (const float*)d_in[8];
    const float* w2u = (const float*)d_in[9];
    const float* b2u = (const float*)d_in[10];
    const int* users     = (const int*)d_in[11];
    const int* histItems = (const int*)d_in[12];
    const int* histSeg   = (const int*)d_in[13];

    float* outUser = (float*)d_out;                          // [16384][128] f32
    float* outItem = (float*)d_out + (size_t)N_USERS * 128;  // [200000][128] f32
    // h buffers live IN-PLACE in the output regions (same byte size per row)
    unsigned short* hItem = (unsigned short*)outItem;        // kappa-packed
    unsigned short* hUser = (unsigned short*)outUser;

    char* ws = (char*)d_ws;
    unsigned short* w1si = (unsigned short*)(ws + 0);        // 131072 B
    unsigned short* w2si = (unsigned short*)(ws + 131072);   // 65536 B
    unsigned short* w1su = (unsigned short*)(ws + 196608);   // 131072 B
    unsigned short* w2su = (unsigned short*)(ws + 327680);   // 65536 B
    float*          hist = (float*)(ws + 393216);            // 8388608 B
    const size_t mirrorOff = 8781824;
    const size_t needBytes = mirrorOff + (size_t)N_ITEMS * 128 * 2;
    unsigned short* mirror = (ws_size >= needBytes) ? (unsigned short*)(ws + mirrorOff) : nullptr;

    cvt_all_kernel<<<768, 256, 0, stream>>>(w1i, w2i, w1u, w2u, w1si, w2si, w1su, w2su);

    // items: L1 (kappa-h into outItem region) -> L2 (in-place finalize + mirror)
    tower_l1_kernel<<<256, 512, 0, stream>>>(
        text, gcnItem, nullptr, w1si, b1i, hItem, N_ITEMS / 16);
    tower_l2_kernel<<<512, 512, 0, stream>>>(
        hItem, w2si, b2i, outItem, mirror, N_ITEMS / 16);

    pool3_kernel<<<N_USERS / 4, 256, 0, stream>>>(mirror, outItem, histItems, histSeg, hist);

    // users: gather gcn_user rows via `users`, concat with hist
    tower_l1_kernel<<<128, 512, 0, stream>>>(
        gcnUser, hist, users, w1su, b1u, hUser, N_USERS / 16);
    tower_l2_kernel<<<128, 512, 0, stream>>>(
        hUser, w2su, b2u, outUser, nullptr, N_USERS / 16);
}

// Round 7
// 787.830 us; speedup vs baseline: 1.4598x; 1.1239x over previous
//
#include <hip/hip_runtime.h>
#include <stdint.h>

#define N_ITEMS   200000
#define N_USERS   16384
#define N_HIST    819200

typedef short bfrag8 __attribute__((ext_vector_type(8)));
typedef float ffrag4 __attribute__((ext_vector_type(4)));

__device__ __forceinline__ unsigned short f2bf(float f) {
    union { float f; unsigned int u; } v; v.f = f;
    unsigned int u = v.u;
    u += 0x7fffu + ((u >> 16) & 1u);   // round-to-nearest-even
    return (unsigned short)(u >> 16);
}

__device__ __forceinline__ ffrag4 mfma16(bfrag8 a, bfrag8 b, ffrag4 c) {
    return __builtin_amdgcn_mfma_f32_16x16x32_bf16(a, b, c, 0, 0, 0);
}

__device__ __forceinline__ bfrag8 pack8(float4 x0, float4 x1) {
    bfrag8 o;
    o[0] = (short)f2bf(x0.x); o[1] = (short)f2bf(x0.y);
    o[2] = (short)f2bf(x0.z); o[3] = (short)f2bf(x0.w);
    o[4] = (short)f2bf(x1.x); o[5] = (short)f2bf(x1.y);
    o[6] = (short)f2bf(x1.z); o[7] = (short)f2bf(x1.w);
    return o;
}

// ---------------------------------------------------------------------------
// K0: weight prep with kappa shuffle for ALL matrices.
//   kappa(kt,lg,j) = 32*kt + 16*(j>>2) + 4*lg + (j&3)
//   o[n*256 + kt*32 + lg*8 + j] = bf16(w[kappa * N + n])
// ---------------------------------------------------------------------------
__global__ void cvt_all_kernel(const float* __restrict__ w1i, const float* __restrict__ w2i,
                               const float* __restrict__ w1u, const float* __restrict__ w2u,
                               unsigned short* __restrict__ o1i, unsigned short* __restrict__ o2i,
                               unsigned short* __restrict__ o1u, unsigned short* __restrict__ o2u) {
    int id = blockIdx.x * 256 + threadIdx.x;        // 0..196607
    const float* w; unsigned short* o; int local; int N;
    if (id < 65536)       { w = w1i; o = o1i; N = 256; local = id; }
    else if (id < 98304)  { w = w2i; o = o2i; N = 128; local = id - 65536; }
    else if (id < 163840) { w = w1u; o = o1u; N = 256; local = id - 98304; }
    else                  { w = w2u; o = o2u; N = 128; local = id - 163840; }
    int n  = local >> 8;
    int r  = local & 255;
    int kt = r >> 5, lg = (r >> 3) & 3, j = r & 7;
    int k  = 32 * kt + 16 * (j >> 2) + 4 * lg + (j & 3);
    o[local] = f2bf(w[(size_t)k * N + n]);
}

// ---------------------------------------------------------------------------
// L1: h = relu([srcA||srcB] @ W1 + b1), kappa-packed bf16 out.
// Swapped GEMM; lane owns full h rows. W1 (kappa) in XOR-swizzled LDS.
// Barrier-free steady state, 16 rows/wave, grid-stride by wave.
// REGISTER-BUDGETED to <=128 VGPRs (the compiler's empirical cap for 8-wave
// blocks): GEMM split into two n-halves (acc 32 regs instead of 64) and the
// prefetch split into text/gcn phases (in-flight 32 regs instead of 64).
// Peak live ~124: af 32 + aft 16 + a4n 32 + acc 32 + misc.
// ---------------------------------------------------------------------------
#define LOAD_TEXT(tt) do { \
    int r_ = (tt) * 16 + lr; \
    int ra_ = rowIdxA ? rowIdxA[r_] : r_; \
    const char* p_ = (const char*)(srcA + (size_t)ra_ * 128) + lg * 16; \
    _Pragma("unroll") \
    for (int c_ = 0; c_ < 8; ++c_) a4n[c_] = *(const float4*)(p_ + c_ * 64); \
    } while (0)

#define LOAD_GCN(tt) do { \
    int r_ = (tt) * 16 + lr; \
    const char* p_ = (const char*)(srcB + (size_t)r_ * 128) + lg * 16; \
    _Pragma("unroll") \
    for (int c_ = 0; c_ < 8; ++c_) a4n[c_] = *(const float4*)(p_ + c_ * 64); \
    } while (0)

__global__ __launch_bounds__(512, 2) void tower_l1_kernel(
    const float* __restrict__ srcA, const float* __restrict__ srcB,
    const int* __restrict__ rowIdxA,
    const unsigned short* __restrict__ w1s, const float* __restrict__ b1,
    unsigned short* __restrict__ hOut, int nTiles)
{
    __shared__ __align__(16) char smem[131072 + 1024];
    char* sW1 = smem;
    float* sB1 = (float*)(smem + 131072);

    const int tid  = threadIdx.x;
    const int lane = tid & 63;
    const int wv   = tid >> 6;
    const int lr   = lane & 15;
    const int lg   = lane >> 4;
    const int swz  = (lr & 7) << 4;

    {   // stage W1 (kappa layout, XOR-swizzled) + b1
        const uint4* g = (const uint4*)w1s;
#pragma unroll
        for (int i = 0; i < 16; ++i) {
            int c = tid + 512 * i;              // 8192 chunks of 16B
            int n = c >> 5, m16 = c & 31;
            *(uint4*)(sW1 + n * 512 + ((m16 * 16) ^ ((n & 7) << 4))) = g[c];
        }
        if (tid < 256) sB1[tid] = b1[tid];
    }
    __syncthreads();                            // only barrier

    const int stride = (int)gridDim.x * 8;
    int t = (int)blockIdx.x * 8 + wv;

    float4 a4n[8];
    bfrag8 af[8];
    if (t < nTiles) {                           // boot: load+pack tile t
        LOAD_TEXT(t);
#pragma unroll
        for (int c = 0; c < 4; ++c) af[c] = pack8(a4n[2 * c], a4n[2 * c + 1]);
        LOAD_GCN(t);
#pragma unroll
        for (int c = 0; c < 4; ++c) af[4 + c] = pack8(a4n[2 * c], a4n[2 * c + 1]);
    }

    for (; t < nTiles; t += stride) {
        int tn = t + stride;
        const bool pf = (tn < nTiles);
        if (pf) LOAD_TEXT(tn);                  // in flight under GEMM-A

        char* hrow = (char*)hOut + (size_t)(t * 16 + lr) * 512 + lg * 16;

        // ---- GEMM half A: h cols 0..127 (nt 0..7) ----
        {
            ffrag4 acc[8];
#pragma unroll
            for (int nt = 0; nt < 8; ++nt)
                acc[nt] = *(const ffrag4*)(sB1 + nt * 16 + lg * 4);
#pragma unroll
            for (int kt = 0; kt < 8; ++kt) {
#pragma unroll
                for (int nt = 0; nt < 8; ++nt) {
                    bfrag8 w1f = *(const bfrag8*)(sW1 + (nt * 16 + lr) * 512
                                                  + ((kt * 64 + lg * 16) ^ swz));
                    acc[nt] = mfma16(w1f, af[kt], acc[nt]);
                }
            }
#pragma unroll
            for (int p = 0; p < 4; ++p) {
                ffrag4 lo = acc[2 * p], hi = acc[2 * p + 1];
                bfrag8 hb;
                hb[0] = (short)f2bf(fmaxf(lo[0], 0.f));
                hb[1] = (short)f2bf(fmaxf(lo[1], 0.f));
                hb[2] = (short)f2bf(fmaxf(lo[2], 0.f));
                hb[3] = (short)f2bf(fmaxf(lo[3], 0.f));
                hb[4] = (short)f2bf(fmaxf(hi[0], 0.f));
                hb[5] = (short)f2bf(fmaxf(hi[1], 0.f));
                hb[6] = (short)f2bf(fmaxf(hi[2], 0.f));
                hb[7] = (short)f2bf(fmaxf(hi[3], 0.f));
                *(bfrag8*)(hrow + p * 64) = hb;
            }
        }

        // ---- pack prefetched text, then launch gcn prefetch ----
        bfrag8 aft[4];
#pragma unroll
        for (int c = 0; c < 4; ++c) aft[c] = pack8(a4n[2 * c], a4n[2 * c + 1]);
        if (pf) LOAD_GCN(tn);                   // in flight under GEMM-B

        // ---- GEMM half B: h cols 128..255 (nt 8..15) ----
        {
            ffrag4 acc[8];
#pragma unroll
            for (int nt = 0; nt < 8; ++nt)
                acc[nt] = *(const ffrag4*)(sB1 + (8 + nt) * 16 + lg * 4);
#pragma unroll
            for (int kt = 0; kt < 8; ++kt) {
#pragma unroll
                for (int nt = 0; nt < 8; ++nt) {
                    bfrag8 w1f = *(const bfrag8*)(sW1 + ((8 + nt) * 16 + lr) * 512
                                                  + ((kt * 64 + lg * 16) ^ swz));
                    acc[nt] = mfma16(w1f, af[kt], acc[nt]);
                }
            }
#pragma unroll
            for (int p = 0; p < 4; ++p) {
                ffrag4 lo = acc[2 * p], hi = acc[2 * p + 1];
                bfrag8 hb;
                hb[0] = (short)f2bf(fmaxf(lo[0], 0.f));
                hb[1] = (short)f2bf(fmaxf(lo[1], 0.f));
                hb[2] = (short)f2bf(fmaxf(lo[2], 0.f));
                hb[3] = (short)f2bf(fmaxf(lo[3], 0.f));
                hb[4] = (short)f2bf(fmaxf(hi[0], 0.f));
                hb[5] = (short)f2bf(fmaxf(hi[1], 0.f));
                hb[6] = (short)f2bf(fmaxf(hi[2], 0.f));
                hb[7] = (short)f2bf(fmaxf(hi[3], 0.f));
                *(bfrag8*)(hrow + (4 + p) * 64) = hb;
            }
        }

        // ---- finalize fragments for next iteration ----
#pragma unroll
        for (int c = 0; c < 4; ++c) af[c] = aft[c];
#pragma unroll
        for (int c = 0; c < 4; ++c) af[4 + c] = pack8(a4n[2 * c], a4n[2 * c + 1]);
    }
}

// ---------------------------------------------------------------------------
// L2: y = h @ W2 + b2, L2-normalized. IN-PLACE: hIn (kappa-packed bf16
// [rows][256]) aliases out (f32 [rows][128]); each row fully read to regs by
// its owning wave before overwrite. W2 (kappa) in swizzled LDS.
// Live set ~80 regs — fits the 128 cap of (512,2) without spills.
// ---------------------------------------------------------------------------
__global__ __launch_bounds__(512, 2) void tower_l2_kernel(
    const unsigned short* hIn,               // aliases out — no restrict!
    const unsigned short* __restrict__ w2s, const float* __restrict__ b2,
    float* out, unsigned short* __restrict__ mirror, int nTiles)
{
    __shared__ __align__(16) char smem2[65536 + 512];
    char* sW2 = smem2;
    float* sB2 = (float*)(smem2 + 65536);

    const int tid  = threadIdx.x;
    const int lane = tid & 63;
    const int wv   = tid >> 6;
    const int lr   = lane & 15;
    const int lg   = lane >> 4;
    const int swz  = (lr & 7) << 4;

    {   // stage W2 (kappa layout, swizzled) + b2
        const uint4* g = (const uint4*)w2s;
#pragma unroll
        for (int i = 0; i < 8; ++i) {
            int c = tid + 512 * i;              // 4096 chunks of 16B
            int n = c >> 5, m16 = c & 31;
            *(uint4*)(sW2 + n * 512 + ((m16 * 16) ^ ((n & 7) << 4))) = g[c];
        }
        if (tid < 128) sB2[tid] = b2[tid];
    }
    __syncthreads();                           // only barrier

    const int stride = (int)gridDim.x * 8;
    for (int t = (int)blockIdx.x * 8 + wv; t < nTiles; t += stride) {
        // load h row (kappa-packed): 8 x 16B at row*512 + kt*64 + lg*16
        const char* hrow = (const char*)hIn + (size_t)(t * 16 + lr) * 512 + lg * 16;
        bfrag8 hf[8];
#pragma unroll
        for (int kt = 0; kt < 8; ++kt)
            hf[kt] = *(const bfrag8*)(hrow + kt * 64);

        ffrag4 acc2[8];
#pragma unroll
        for (int ot = 0; ot < 8; ++ot)
            acc2[ot] = *(const ffrag4*)(sB2 + ot * 16 + lg * 4);   // bias init
#pragma unroll
        for (int kt = 0; kt < 8; ++kt) {
#pragma unroll
            for (int ot = 0; ot < 8; ++ot) {
                bfrag8 w2f = *(const bfrag8*)(sW2 + (ot * 16 + lr) * 512
                                              + ((kt * 64 + lg * 16) ^ swz));
                acc2[ot] = mfma16(w2f, hf[kt], acc2[ot]);
            }
        }

        // lane-local norm: lane holds y[row t*16+lr][ot*16+4lg+q]
        float psum = 0.f;
#pragma unroll
        for (int ot = 0; ot < 8; ++ot)
#pragma unroll
            for (int r = 0; r < 4; ++r) psum += acc2[ot][r] * acc2[ot][r];
        psum += __shfl_xor(psum, 16);
        psum += __shfl_xor(psum, 32);
        float sc = 1.f / fmaxf(sqrtf(psum), 1e-12f);

        int m = t * 16 + lr;
        float* orow = out + (size_t)m * 128 + lg * 4;
#pragma unroll
        for (int ot = 0; ot < 8; ++ot) {
            float4 v4;
            v4.x = acc2[ot][0] * sc; v4.y = acc2[ot][1] * sc;
            v4.z = acc2[ot][2] * sc; v4.w = acc2[ot][3] * sc;
            *(float4*)(orow + ot * 16) = v4;    // 64 B/row per instruction
            if (mirror) {
                uint2 mm;
                mm.x = (unsigned)f2bf(v4.x) | ((unsigned)f2bf(v4.y) << 16);
                mm.y = (unsigned)f2bf(v4.z) | ((unsigned)f2bf(v4.w) << 16);
                *(uint2*)(mirror + (size_t)m * 128 + ot * 16 + 4 * lg) = mm;
            }
        }
    }
}

// ---------------------------------------------------------------------------
// Pool: per-user segment mean. 4 waves/block, 1 user/wave, 2 items/iter.
// ---------------------------------------------------------------------------
__global__ __launch_bounds__(256) void pool3_kernel(
    const unsigned short* __restrict__ mirror,
    const float* __restrict__ itemF,
    const int* __restrict__ histItems,
    const int* __restrict__ histSeg,
    float* __restrict__ hist)
{
    const int u = blockIdx.x * 4 + (threadIdx.x >> 6);
    const int lane = threadIdx.x & 63;
    const int half = lane >> 5;
    const int c = lane & 31;

    int lo = 0, hi = N_HIST;
    while (lo < hi) { int m = (lo + hi) >> 1; if (histSeg[m] < u) lo = m + 1; else hi = m; }
    const int s = lo;
    hi = N_HIST;
    while (lo < hi) { int m = (lo + hi) >> 1; if (histSeg[m] < u + 1) lo = m + 1; else hi = m; }
    const int e = lo;

    float s0 = 0.f, s1 = 0.f, s2 = 0.f, s3 = 0.f;
    if (mirror) {
        for (int i = s + half; i < e; i += 2) {
            int idx = histItems[i];
            uint2 v = *(const uint2*)(mirror + (size_t)idx * 128 + c * 4);
            union { unsigned u; float f; } a, b, cc, d;
            a.u  = v.x << 16; b.u  = v.x & 0xffff0000u;
            cc.u = v.y << 16; d.u  = v.y & 0xffff0000u;
            s0 += a.f; s1 += b.f; s2 += cc.f; s3 += d.f;
        }
    } else {
        for (int i = s + half; i < e; i += 2) {
            int idx = histItems[i];
            float4 v = *(const float4*)(itemF + (size_t)idx * 128 + c * 4);
            s0 += v.x; s1 += v.y; s2 += v.z; s3 += v.w;
        }
    }
    s0 += __shfl_xor(s0, 32);
    s1 += __shfl_xor(s1, 32);
    s2 += __shfl_xor(s2, 32);
    s3 += __shfl_xor(s3, 32);
    if (half == 0) {
        float inv = (e > s) ? 1.f / (float)(e - s) : 0.f;
        float4 r; r.x = s0 * inv; r.y = s1 * inv; r.z = s2 * inv; r.w = s3 * inv;
        *(float4*)(hist + (size_t)u * 128 + c * 4) = r;
    }
}

// ---------------------------------------------------------------------------
extern "C" void kernel_launch(void* const* d_in, const int* in_sizes, int n_in,
                              void* d_out, int out_size, void* d_ws, size_t ws_size,
                              hipStream_t stream) {
    const float* text    = (const float*)d_in[0];
    const float* gcnItem = (const float*)d_in[1];
    const float* gcnUser = (const float*)d_in[2];
    const float* w1i = (const float*)d_in[3];
    const float* b1i = (const float*)d_in[4];
    const float* w2i = (const float*)d_in[5];
    const float* b2i = (const float*)d_in[6];
    const float* w1u = (const float*)d_in[7];
    const float* b1u = (const float*)d_in[8];
    const float* w2u = (const float*)d_in[9];
    const float* b2u = (const float*)d_in[10];
    const int* users     = (const int*)d_in[11];
    const int* histItems = (const int*)d_in[12];
    const int* histSeg   = (const int*)d_in[13];

    float* outUser = (float*)d_out;                          // [16384][128] f32
    float* outItem = (float*)d_out + (size_t)N_USERS * 128;  // [200000][128] f32
    // h buffers live IN-PLACE in the output regions (same byte size per row)
    unsigned short* hItem = (unsigned short*)outItem;        // kappa-packed
    unsigned short* hUser = (unsigned short*)outUser;

    char* ws = (char*)d_ws;
    unsigned short* w1si = (unsigned short*)(ws + 0);        // 131072 B
    unsigned short* w2si = (unsigned short*)(ws + 131072);   // 65536 B
    unsigned short* w1su = (unsigned short*)(ws + 196608);   // 131072 B
    unsigned short* w2su = (unsigned short*)(ws + 327680);   // 65536 B
    float*          hist = (float*)(ws + 393216);            // 8388608 B
    const size_t mirrorOff = 8781824;
    const size_t needBytes = mirrorOff + (size_t)N_ITEMS * 128 * 2;
    unsigned short* mirror = (ws_size >= needBytes) ? (unsigned short*)(ws + mirrorOff) : nullptr;

    cvt_all_kernel<<<768, 256, 0, stream>>>(w1i, w2i, w1u, w2u, w1si, w2si, w1su, w2su);

    // items: L1 (kappa-h into outItem region) -> L2 (in-place finalize + mirror)
    tower_l1_kernel<<<256, 512, 0, stream>>>(
        text, gcnItem, nullptr, w1si, b1i, hItem, N_ITEMS / 16);
    tower_l2_kernel<<<512, 512, 0, stream>>>(
        hItem, w2si, b2i, outItem, mirror, N_ITEMS / 16);

    pool3_kernel<<<N_USERS / 4, 256, 0, stream>>>(mirror, outItem, histItems, histSeg, hist);

    // users: gather gcn_user rows via `users`, concat with hist
    tower_l1_kernel<<<128, 512, 0, stream>>>(
        gcnUser, hist, users, w1su, b1u, hUser, N_USERS / 16);
    tower_l2_kernel<<<128, 512, 0, stream>>>(
        hUser, w2su, b2u, outUser, nullptr, N_USERS / 16);
}

// Round 8
// 573.044 us; speedup vs baseline: 2.0069x; 1.3748x over previous
//
#include <hip/hip_runtime.h>
#include <stdint.h>

#define N_ITEMS   200000
#define N_USERS   16384
#define N_HIST    819200

typedef short bfrag8 __attribute__((ext_vector_type(8)));
typedef float ffrag4 __attribute__((ext_vector_type(4)));

__device__ __forceinline__ unsigned short f2bf(float f) {
    union { float f; unsigned int u; } v; v.f = f;
    unsigned int u = v.u;
    u += 0x7fffu + ((u >> 16) & 1u);   // round-to-nearest-even
    return (unsigned short)(u >> 16);
}

__device__ __forceinline__ ffrag4 mfma16(bfrag8 a, bfrag8 b, ffrag4 c) {
    return __builtin_amdgcn_mfma_f32_16x16x32_bf16(a, b, c, 0, 0, 0);
}

__device__ __forceinline__ bfrag8 pack8(float4 x0, float4 x1) {
    bfrag8 o;
    o[0] = (short)f2bf(x0.x); o[1] = (short)f2bf(x0.y);
    o[2] = (short)f2bf(x0.z); o[3] = (short)f2bf(x0.w);
    o[4] = (short)f2bf(x1.x); o[5] = (short)f2bf(x1.y);
    o[6] = (short)f2bf(x1.z); o[7] = (short)f2bf(x1.w);
    return o;
}

// ---------------------------------------------------------------------------
// K0: weight prep with kappa shuffle for ALL matrices.
//   kappa(kt,lg,j) = 32*kt + 16*(j>>2) + 4*lg + (j&3)
//   o[n*256 + kt*32 + lg*8 + j] = bf16(w[kappa * N + n])
// ---------------------------------------------------------------------------
__global__ void cvt_all_kernel(const float* __restrict__ w1i, const float* __restrict__ w2i,
                               const float* __restrict__ w1u, const float* __restrict__ w2u,
                               unsigned short* __restrict__ o1i, unsigned short* __restrict__ o2i,
                               unsigned short* __restrict__ o1u, unsigned short* __restrict__ o2u) {
    int id = blockIdx.x * 256 + threadIdx.x;        // 0..196607
    const float* w; unsigned short* o; int local; int N;
    if (id < 65536)       { w = w1i; o = o1i; N = 256; local = id; }
    else if (id < 98304)  { w = w2i; o = o2i; N = 128; local = id - 65536; }
    else if (id < 163840) { w = w1u; o = o1u; N = 256; local = id - 98304; }
    else                  { w = w2u; o = o2u; N = 128; local = id - 163840; }
    int n  = local >> 8;
    int r  = local & 255;
    int kt = r >> 5, lg = (r >> 3) & 3, j = r & 7;
    int k  = 32 * kt + 16 * (j >> 2) + 4 * lg + (j & 3);
    o[local] = f2bf(w[(size_t)k * N + n]);
}

// ---------------------------------------------------------------------------
// L1: h = relu([srcA||srcB] @ W1 + b1), kappa-packed bf16 out.
// Swapped GEMM; lane owns full h rows. W1 (kappa) in XOR-swizzled LDS.
// Barrier-free steady state, 16 rows/wave, grid-stride by wave.
// 256-THREAD BLOCKS (4 waves): the compiler grants ~224 VGPRs for 4-wave
// blocks (hardware-verified in round 2: VGPR_Count=224) but pins 8-wave
// blocks at 128, spilling ~75 regs/tile (rounds 3-7: 826-914 MB FETCH,
// 2% MfmaUtil). Live set here ~185 regs: a4 64 + af 32 + acc1 64 + misc.
// LDS 132 KB -> 1 block/CU.
// ---------------------------------------------------------------------------
#define LOAD_X(tt)  do { \
    int r_ = (tt) * 16 + lr; \
    int ra_ = rowIdxA ? rowIdxA[r_] : r_; \
    const char* pA_ = (const char*)(srcA + (size_t)ra_ * 128) + lg * 16; \
    const char* pB_ = (const char*)(srcB + (size_t)r_ * 128) + lg * 16; \
    _Pragma("unroll") \
    for (int c_ = 0; c_ < 8; ++c_) a4[c_]     = *(const float4*)(pA_ + c_ * 64); \
    _Pragma("unroll") \
    for (int c_ = 0; c_ < 8; ++c_) a4[8 + c_] = *(const float4*)(pB_ + c_ * 64); \
    } while (0)

__global__ __launch_bounds__(256, 1) void tower_l1_kernel(
    const float* __restrict__ srcA, const float* __restrict__ srcB,
    const int* __restrict__ rowIdxA,
    const unsigned short* __restrict__ w1s, const float* __restrict__ b1,
    unsigned short* __restrict__ hOut, int nTiles)
{
    __shared__ __align__(16) char smem[131072 + 1024];
    char* sW1 = smem;
    float* sB1 = (float*)(smem + 131072);

    const int tid  = threadIdx.x;
    const int lane = tid & 63;
    const int wv   = tid >> 6;          // 0..3
    const int lr   = lane & 15;
    const int lg   = lane >> 4;
    const int swz  = (lr & 7) << 4;

    {   // stage W1 (kappa layout, XOR-swizzled) + b1
        const uint4* g = (const uint4*)w1s;
#pragma unroll
        for (int i = 0; i < 32; ++i) {
            int c = tid + 256 * i;              // 8192 chunks of 16B
            int n = c >> 5, m16 = c & 31;
            *(uint4*)(sW1 + n * 512 + ((m16 * 16) ^ ((n & 7) << 4))) = g[c];
        }
        sB1[tid] = b1[tid];
    }
    __syncthreads();                            // only barrier

    const int stride = (int)gridDim.x * 4;
    int t = (int)blockIdx.x * 4 + wv;
    float4 a4[16];
    if (t < nTiles) LOAD_X(t);

    for (; t < nTiles; t += stride) {
        bfrag8 af[8];
#pragma unroll
        for (int kt = 0; kt < 8; ++kt) af[kt] = pack8(a4[2 * kt], a4[2 * kt + 1]);
        int tn = t + stride;
        if (tn < nTiles) LOAD_X(tn);            // in flight under the GEMM

        ffrag4 acc1[16];
#pragma unroll
        for (int nt = 0; nt < 16; ++nt)
            acc1[nt] = *(const ffrag4*)(sB1 + nt * 16 + lg * 4);
#pragma unroll
        for (int kt = 0; kt < 8; ++kt) {
#pragma unroll
            for (int nt = 0; nt < 16; ++nt) {
                bfrag8 w1f = *(const bfrag8*)(sW1 + (nt * 16 + lr) * 512
                                              + ((kt * 64 + lg * 16) ^ swz));
                acc1[nt] = mfma16(w1f, af[kt], acc1[nt]);
            }
        }

        // h store, kappa-packed: lane writes 16B at row*512 + p*64 + lg*16
        char* hrow = (char*)hOut + (size_t)(t * 16 + lr) * 512 + lg * 16;
#pragma unroll
        for (int p = 0; p < 8; ++p) {
            ffrag4 lo = acc1[2 * p], hi = acc1[2 * p + 1];
            bfrag8 hb;
            hb[0] = (short)f2bf(fmaxf(lo[0], 0.f));
            hb[1] = (short)f2bf(fmaxf(lo[1], 0.f));
            hb[2] = (short)f2bf(fmaxf(lo[2], 0.f));
            hb[3] = (short)f2bf(fmaxf(lo[3], 0.f));
            hb[4] = (short)f2bf(fmaxf(hi[0], 0.f));
            hb[5] = (short)f2bf(fmaxf(hi[1], 0.f));
            hb[6] = (short)f2bf(fmaxf(hi[2], 0.f));
            hb[7] = (short)f2bf(fmaxf(hi[3], 0.f));
            *(bfrag8*)(hrow + p * 64) = hb;
        }
    }
}

// ---------------------------------------------------------------------------
// L2: y = h @ W2 + b2, L2-normalized. IN-PLACE: hIn (kappa-packed bf16
// [rows][256]) aliases out (f32 [rows][128]); each row fully read to regs by
// its owning wave before overwrite. W2 (kappa) in swizzled LDS.
// 256-thread blocks, live ~90 regs; LDS 66 KB -> 2 blocks/CU (2 waves/SIMD).
// ---------------------------------------------------------------------------
__global__ __launch_bounds__(256, 2) void tower_l2_kernel(
    const unsigned short* hIn,               // aliases out — no restrict!
    const unsigned short* __restrict__ w2s, const float* __restrict__ b2,
    float* out, unsigned short* __restrict__ mirror, int nTiles)
{
    __shared__ __align__(16) char smem2[65536 + 512];
    char* sW2 = smem2;
    float* sB2 = (float*)(smem2 + 65536);

    const int tid  = threadIdx.x;
    const int lane = tid & 63;
    const int wv   = tid >> 6;          // 0..3
    const int lr   = lane & 15;
    const int lg   = lane >> 4;
    const int swz  = (lr & 7) << 4;

    {   // stage W2 (kappa layout, swizzled) + b2
        const uint4* g = (const uint4*)w2s;
#pragma unroll
        for (int i = 0; i < 16; ++i) {
            int c = tid + 256 * i;              // 4096 chunks of 16B
            int n = c >> 5, m16 = c & 31;
            *(uint4*)(sW2 + n * 512 + ((m16 * 16) ^ ((n & 7) << 4))) = g[c];
        }
        if (tid < 128) sB2[tid] = b2[tid];
    }
    __syncthreads();                           // only barrier

    const int stride = (int)gridDim.x * 4;
    for (int t = (int)blockIdx.x * 4 + wv; t < nTiles; t += stride) {
        // load h row (kappa-packed): 8 x 16B at row*512 + kt*64 + lg*16
        const char* hrow = (const char*)hIn + (size_t)(t * 16 + lr) * 512 + lg * 16;
        bfrag8 hf[8];
#pragma unroll
        for (int kt = 0; kt < 8; ++kt)
            hf[kt] = *(const bfrag8*)(hrow + kt * 64);

        ffrag4 acc2[8];
#pragma unroll
        for (int ot = 0; ot < 8; ++ot)
            acc2[ot] = *(const ffrag4*)(sB2 + ot * 16 + lg * 4);   // bias init
#pragma unroll
        for (int kt = 0; kt < 8; ++kt) {
#pragma unroll
            for (int ot = 0; ot < 8; ++ot) {
                bfrag8 w2f = *(const bfrag8*)(sW2 + (ot * 16 + lr) * 512
                                              + ((kt * 64 + lg * 16) ^ swz));
                acc2[ot] = mfma16(w2f, hf[kt], acc2[ot]);
            }
        }

        // lane-local norm: lane holds y[row t*16+lr][ot*16+4lg+q]
        float psum = 0.f;
#pragma unroll
        for (int ot = 0; ot < 8; ++ot)
#pragma unroll
            for (int r = 0; r < 4; ++r) psum += acc2[ot][r] * acc2[ot][r];
        psum += __shfl_xor(psum, 16);
        psum += __shfl_xor(psum, 32);
        float sc = 1.f / fmaxf(sqrtf(psum), 1e-12f);

        int m = t * 16 + lr;
        float* orow = out + (size_t)m * 128 + lg * 4;
#pragma unroll
        for (int ot = 0; ot < 8; ++ot) {
            float4 v4;
            v4.x = acc2[ot][0] * sc; v4.y = acc2[ot][1] * sc;
            v4.z = acc2[ot][2] * sc; v4.w = acc2[ot][3] * sc;
            *(float4*)(orow + ot * 16) = v4;    // 64 B/row per instruction
            if (mirror) {
                uint2 mm;
                mm.x = (unsigned)f2bf(v4.x) | ((unsigned)f2bf(v4.y) << 16);
                mm.y = (unsigned)f2bf(v4.z) | ((unsigned)f2bf(v4.w) << 16);
                *(uint2*)(mirror + (size_t)m * 128 + ot * 16 + 4 * lg) = mm;
            }
        }
    }
}

// ---------------------------------------------------------------------------
// Pool: per-user segment mean. 4 waves/block, 1 user/wave, 2 items/iter.
// ---------------------------------------------------------------------------
__global__ __launch_bounds__(256) void pool3_kernel(
    const unsigned short* __restrict__ mirror,
    const float* __restrict__ itemF,
    const int* __restrict__ histItems,
    const int* __restrict__ histSeg,
    float* __restrict__ hist)
{
    const int u = blockIdx.x * 4 + (threadIdx.x >> 6);
    const int lane = threadIdx.x & 63;
    const int half = lane >> 5;
    const int c = lane & 31;

    int lo = 0, hi = N_HIST;
    while (lo < hi) { int m = (lo + hi) >> 1; if (histSeg[m] < u) lo = m + 1; else hi = m; }
    const int s = lo;
    hi = N_HIST;
    while (lo < hi) { int m = (lo + hi) >> 1; if (histSeg[m] < u + 1) lo = m + 1; else hi = m; }
    const int e = lo;

    float s0 = 0.f, s1 = 0.f, s2 = 0.f, s3 = 0.f;
    if (mirror) {
        for (int i = s + half; i < e; i += 2) {
            int idx = histItems[i];
            uint2 v = *(const uint2*)(mirror + (size_t)idx * 128 + c * 4);
            union { unsigned u; float f; } a, b, cc, d;
            a.u  = v.x << 16; b.u  = v.x & 0xffff0000u;
            cc.u = v.y << 16; d.u  = v.y & 0xffff0000u;
            s0 += a.f; s1 += b.f; s2 += cc.f; s3 += d.f;
        }
    } else {
        for (int i = s + half; i < e; i += 2) {
            int idx = histItems[i];
            float4 v = *(const float4*)(itemF + (size_t)idx * 128 + c * 4);
            s0 += v.x; s1 += v.y; s2 += v.z; s3 += v.w;
        }
    }
    s0 += __shfl_xor(s0, 32);
    s1 += __shfl_xor(s1, 32);
    s2 += __shfl_xor(s2, 32);
    s3 += __shfl_xor(s3, 32);
    if (half == 0) {
        float inv = (e > s) ? 1.f / (float)(e - s) : 0.f;
        float4 r; r.x = s0 * inv; r.y = s1 * inv; r.z = s2 * inv; r.w = s3 * inv;
        *(float4*)(hist + (size_t)u * 128 + c * 4) = r;
    }
}

// ---------------------------------------------------------------------------
extern "C" void kernel_launch(void* const* d_in, const int* in_sizes, int n_in,
                              void* d_out, int out_size, void* d_ws, size_t ws_size,
                              hipStream_t stream) {
    const float* text    = (const float*)d_in[0];
    const float* gcnItem = (const float*)d_in[1];
    const float* gcnUser = (const float*)d_in[2];
    const float* w1i = (const float*)d_in[3];
    const float* b1i = (const float*)d_in[4];
    const float* w2i = (const float*)d_in[5];
    const float* b2i = (const float*)d_in[6];
    const float* w1u = (const float*)d_in[7];
    const float* b1u = (const float*)d_in[8];
    const float* w2u = (const float*)d_in[9];
    const float* b2u = (const float*)d_in[10];
    const int* users     = (const int*)d_in[11];
    const int* histItems = (const int*)d_in[12];
    const int* histSeg   = (const int*)d_in[13];

    float* outUser = (float*)d_out;                          // [16384][128] f32
    float* outItem = (float*)d_out + (size_t)N_USERS * 128;  // [200000][128] f32
    // h buffers live IN-PLACE in the output regions (same byte size per row)
    unsigned short* hItem = (unsigned short*)outItem;        // kappa-packed
    unsigned short* hUser = (unsigned short*)outUser;

    char* ws = (char*)d_ws;
    unsigned short* w1si = (unsigned short*)(ws + 0);        // 131072 B
    unsigned short* w2si = (unsigned short*)(ws + 131072);   // 65536 B
    unsigned short* w1su = (unsigned short*)(ws + 196608);   // 131072 B
    unsigned short* w2su = (unsigned short*)(ws + 327680);   // 65536 B
    float*          hist = (float*)(ws + 393216);            // 8388608 B
    const size_t mirrorOff = 8781824;
    const size_t needBytes = mirrorOff + (size_t)N_ITEMS * 128 * 2;
    unsigned short* mirror = (ws_size >= needBytes) ? (unsigned short*)(ws + mirrorOff) : nullptr;

    cvt_all_kernel<<<768, 256, 0, stream>>>(w1i, w2i, w1u, w2u, w1si, w2si, w1su, w2su);

    // items: L1 (kappa-h into outItem region) -> L2 (in-place finalize + mirror)
    tower_l1_kernel<<<256, 256, 0, stream>>>(
        text, gcnItem, nullptr, w1si, b1i, hItem, N_ITEMS / 16);
    tower_l2_kernel<<<512, 256, 0, stream>>>(
        hItem, w2si, b2i, outItem, mirror, N_ITEMS / 16);

    pool3_kernel<<<N_USERS / 4, 256, 0, stream>>>(mirror, outItem, histItems, histSeg, hist);

    // users: gather gcn_user rows via `users`, concat with hist
    tower_l1_kernel<<<256, 256, 0, stream>>>(
        gcnUser, hist, users, w1su, b1u, hUser, N_USERS / 16);
    tower_l2_kernel<<<128, 256, 0, stream>>>(
        hUser, w2su, b2u, outUser, nullptr, N_USERS / 16);
}